// Round 1
// baseline (120.797 us; speedup 1.0000x reference)
//
#include <hip/hip_runtime.h>

// HMM posterior: out[b,t,s] = log_softmax_s(alphahat[t]+betahat[t]) — batch-independent
// (scalar emission terms cancel in the softmax; observations never needed).
// Linear-space with per-product max-rescale: p_t = p0 @ E^t, q_t = E^(T-1-t) @ 1, E = exp(A).

#define SS 64
#define TT 1024
#define NK 10   // powers E^(2^k), k=0..9

__device__ __forceinline__ void fma4(float4& acc, float a, float4 b) {
    acc.x = fmaf(a, b.x, acc.x);
    acc.y = fmaf(a, b.y, acc.y);
    acc.z = fmaf(a, b.z, acc.z);
    acc.w = fmaf(a, b.w, acc.w);
}

// ---- Kernel A: M[k] = normalized E^(2^k), plus transposes Mt[k] (for the beta direction).
// One block, 256 threads, 9 sequential 64x64x64 fp32 GEMMs in LDS (4x4 register tiles).
__global__ __launch_bounds__(256) void hmm_powers(const float* __restrict__ logA,
                                                  float* __restrict__ M,
                                                  float* __restrict__ Mt) {
    const int LD = 68;                 // padded LDS row stride (bank-conflict-free)
    __shared__ float bufA[64 * 68];
    __shared__ float bufB[64 * 68];
    __shared__ float red[256];
    const int tid = threadIdx.x;

    // M0 = exp(logA), normalized by its max entry
    float4 ev[4];
    float lmax = 0.f;
    for (int c = 0; c < 4; ++c) {
        float4 v = ((const float4*)logA)[tid + 256 * c];
        float4 w;
        w.x = __expf(v.x); w.y = __expf(v.y); w.z = __expf(v.z); w.w = __expf(v.w);
        ev[c] = w;
        lmax = fmaxf(lmax, fmaxf(fmaxf(w.x, w.y), fmaxf(w.z, w.w)));
    }
    red[tid] = lmax;
    __syncthreads();
    for (int s = 128; s > 0; s >>= 1) {
        if (tid < s) red[tid] = fmaxf(red[tid], red[tid + s]);
        __syncthreads();
    }
    const float scale0 = 1.f / red[0];
    for (int c = 0; c < 4; ++c) {
        int f = tid + 256 * c;   // float4 index; elements f*4 .. f*4+3 share one row
        int idx = f * 4;
        int i = idx >> 6;
        int j = idx & 63;
        float4 w = ev[c];
        w.x *= scale0; w.y *= scale0; w.z *= scale0; w.w *= scale0;
        *(float4*)&bufA[i * LD + j] = w;
        ((float4*)M)[f] = w;
        Mt[(j + 0) * 64 + i] = w.x;
        Mt[(j + 1) * 64 + i] = w.y;
        Mt[(j + 2) * 64 + i] = w.z;
        Mt[(j + 3) * 64 + i] = w.w;
    }

    float* cur = bufA;
    float* nxt = bufB;
    const int rg = tid >> 4, cg = tid & 15;
    const int r0 = rg * 4, j0 = cg * 4;

    for (int k = 1; k < NK; ++k) {
        __syncthreads();   // cur fully written (step 0 or previous iteration)
        float4 acc0 = make_float4(0.f, 0.f, 0.f, 0.f);
        float4 acc1 = acc0, acc2 = acc0, acc3 = acc0;
        #pragma unroll
        for (int i0 = 0; i0 < 64; i0 += 4) {
            float4 a0 = *(const float4*)&cur[(r0 + 0) * LD + i0];
            float4 a1 = *(const float4*)&cur[(r0 + 1) * LD + i0];
            float4 a2 = *(const float4*)&cur[(r0 + 2) * LD + i0];
            float4 a3 = *(const float4*)&cur[(r0 + 3) * LD + i0];
            float4 b0 = *(const float4*)&cur[(i0 + 0) * LD + j0];
            float4 b1 = *(const float4*)&cur[(i0 + 1) * LD + j0];
            float4 b2 = *(const float4*)&cur[(i0 + 2) * LD + j0];
            float4 b3 = *(const float4*)&cur[(i0 + 3) * LD + j0];
            fma4(acc0, a0.x, b0); fma4(acc0, a0.y, b1); fma4(acc0, a0.z, b2); fma4(acc0, a0.w, b3);
            fma4(acc1, a1.x, b0); fma4(acc1, a1.y, b1); fma4(acc1, a1.z, b2); fma4(acc1, a1.w, b3);
            fma4(acc2, a2.x, b0); fma4(acc2, a2.y, b1); fma4(acc2, a2.z, b2); fma4(acc2, a2.w, b3);
            fma4(acc3, a3.x, b0); fma4(acc3, a3.y, b1); fma4(acc3, a3.z, b2); fma4(acc3, a3.w, b3);
        }
        float m0 = fmaxf(fmaxf(acc0.x, acc0.y), fmaxf(acc0.z, acc0.w));
        float m1 = fmaxf(fmaxf(acc1.x, acc1.y), fmaxf(acc1.z, acc1.w));
        float m2 = fmaxf(fmaxf(acc2.x, acc2.y), fmaxf(acc2.z, acc2.w));
        float m3 = fmaxf(fmaxf(acc3.x, acc3.y), fmaxf(acc3.z, acc3.w));
        red[tid] = fmaxf(fmaxf(m0, m1), fmaxf(m2, m3));
        __syncthreads();
        for (int s = 128; s > 0; s >>= 1) {
            if (tid < s) red[tid] = fmaxf(red[tid], red[tid + s]);
            __syncthreads();
        }
        const float sc = 1.f / red[0];
        float* Mk  = M  + (k << 12);
        float* Mtk = Mt + (k << 12);
        float4 accs[4] = {acc0, acc1, acc2, acc3};
        #pragma unroll
        for (int rr = 0; rr < 4; ++rr) {
            float4 w = accs[rr];
            w.x *= sc; w.y *= sc; w.z *= sc; w.w *= sc;
            *(float4*)&nxt[(r0 + rr) * LD + j0] = w;
            *(float4*)&Mk[(r0 + rr) * 64 + j0] = w;
            Mtk[(j0 + 0) * 64 + r0 + rr] = w.x;
            Mtk[(j0 + 1) * 64 + r0 + rr] = w.y;
            Mtk[(j0 + 2) * 64 + r0 + rr] = w.z;
            Mtk[(j0 + 3) * 64 + r0 + rr] = w.w;
        }
        float* tmp = cur; cur = nxt; nxt = tmp;
    }
}

// ---- Kernel C: per-t binary-decomposition matvecs + softmax row + broadcast write.
// 1024 blocks (one per t) x 256 threads. Wave 0 computes p_t, wave 1 computes q_t.
__global__ __launch_bounds__(256) void hmm_gamma(const float* __restrict__ M,
                                                 const float* __restrict__ Mt,
                                                 const float* __restrict__ logInit,
                                                 float* __restrict__ out) {
    const int t = blockIdx.x;
    __shared__ float sp[64];
    __shared__ float sq[64];
    __shared__ float sg[64];
    const int tid  = threadIdx.x;
    const int lane = tid & 63;
    const int w    = tid >> 6;

    if (w == 0) {
        sp[lane] = __expf(logInit[lane]);          // alphahat_0 direction
        const int e = t;
        for (int k = 0; k < NK; ++k) {
            if ((e >> k) & 1) {
                const float* Mk = M + (k << 12);
                float acc = 0.f;
                #pragma unroll
                for (int i = 0; i < 64; ++i)
                    acc = fmaf(sp[i], Mk[(i << 6) + lane], acc);   // coalesced row reads
                float mx = acc;
                #pragma unroll
                for (int off = 32; off > 0; off >>= 1)
                    mx = fmaxf(mx, __shfl_xor(mx, off, 64));
                sp[lane] = acc * (1.f / mx);
            }
        }
    } else if (w == 1) {
        sq[lane] = 1.f;                            // betahat_{T-1} = 0
        const int e = (TT - 1) - t;
        for (int k = 0; k < NK; ++k) {
            if ((e >> k) & 1) {
                const float* Mk = Mt + (k << 12);
                float acc = 0.f;
                #pragma unroll
                for (int i = 0; i < 64; ++i)
                    acc = fmaf(sq[i], Mk[(i << 6) + lane], acc);
                float mx = acc;
                #pragma unroll
                for (int off = 32; off > 0; off >>= 1)
                    mx = fmaxf(mx, __shfl_xor(mx, off, 64));
                sq[lane] = acc * (1.f / mx);
            }
        }
    }
    __syncthreads();

    if (w == 0) {
        float gv = __logf(sp[lane]) + __logf(sq[lane]);
        float mx = gv;
        #pragma unroll
        for (int off = 32; off > 0; off >>= 1)
            mx = fmaxf(mx, __shfl_xor(mx, off, 64));
        float ex = __expf(gv - mx);
        float sm = ex;
        #pragma unroll
        for (int off = 32; off > 0; off >>= 1)
            sm += __shfl_xor(sm, off, 64);
        sg[lane] = gv - mx - __logf(sm);
    }
    __syncthreads();

    // Broadcast the 64-float row to all 256 batches: 64 KB per block, float4 coalesced.
    const int s4 = tid & 15;
    const int b0 = tid >> 4;
    float4 val = ((const float4*)sg)[s4];
    float4* o4 = (float4*)out;
    const size_t trow = (size_t)t * 16 + s4;
    #pragma unroll
    for (int it = 0; it < 16; ++it) {
        int b = (it << 4) + b0;
        o4[(size_t)b * 16384 + trow] = val;
    }
}

extern "C" void kernel_launch(void* const* d_in, const int* in_sizes, int n_in,
                              void* d_out, int out_size, void* d_ws, size_t ws_size,
                              hipStream_t stream) {
    // inputs: [0] observations (unused — cancels), [1] log_transition (64x64 f32),
    //         [2] log_initial (64 f32), [3] log_emission (unused — cancels)
    const float* logA    = (const float*)d_in[1];
    const float* logInit = (const float*)d_in[2];
    float* M  = (float*)d_ws;              // 10 * 4096 floats
    float* Mt = M + NK * 4096;             // 10 * 4096 floats (total 320 KB of ws)
    hmm_powers<<<1, 256, 0, stream>>>(logA, M, Mt);
    hmm_gamma<<<TT, 256, 0, stream>>>(M, Mt, logInit, (float*)d_out);
}